// Round 6
// baseline (99.448 us; speedup 1.0000x reference)
//
#include <hip/hip_runtime.h>
#include <hip/hip_bf16.h>

typedef __attribute__((ext_vector_type(4))) float f32x4;
typedef __attribute__((ext_vector_type(8))) short short8;

#define NB 8192
#define ND 256
#define NK 32

static __device__ __forceinline__ unsigned short f2bf(float f) {
  return __builtin_bit_cast(unsigned short, __float2bfloat16(f));
}

static __device__ __forceinline__ f32x4 mfma_bf16(short8 a, short8 b, f32x4 c) {
  return __builtin_amdgcn_mfma_f32_16x16x32_bf16(a, b, c, 0, 0, 0);
}

static __device__ __forceinline__ short8 pack_bf16x8(float4 lo, float4 hi) {
  short8 r;
  r[0] = (short)f2bf(lo.x); r[1] = (short)f2bf(lo.y);
  r[2] = (short)f2bf(lo.z); r[3] = (short)f2bf(lo.w);
  r[4] = (short)f2bf(hi.x); r[5] = (short)f2bf(hi.y);
  r[6] = (short)f2bf(hi.z); r[7] = (short)f2bf(hi.w);
  return r;
}

// ---- kernel 0: small prep ---------------------------------------------------
// blocks [0,512)   : Wcat = [W_mu; W_sig] -> bf16 [512][256]
// blocks [512,544) : Bc bf16 [32][512]; c3k[k]; ckk[k]; block 512 zeroes cnt
__global__ __launch_bounds__(256) void prep_k(const float* __restrict__ wmu,
                                              const float* __restrict__ wsig,
                                              __hip_bfloat16* __restrict__ wb,
                                              const float* __restrict__ mu_c,
                                              const float* __restrict__ lsc,
                                              __hip_bfloat16* __restrict__ Bc,
                                              float* __restrict__ c3k,
                                              float* __restrict__ ckk,
                                              int* __restrict__ cnt) {
  __shared__ float red1[4], red2[4];
  const int blk = blockIdx.x, tid = threadIdx.x;
  if (blk < 512) {
    int i = blk * 256 + tid;
    float v = (i < 65536) ? wmu[i] : wsig[i - 65536];
    wb[i] = __float2bfloat16(v);
  } else {
    if (blk == 512 && tid == 0) *cnt = 0;
    int k = blk - 512;
    int d = tid;
    float l = lsc[k * ND + d];
    float inv = __expf(-l);
    float mc = mu_c[k * ND + d];
    Bc[k * 512 + d]       = __float2bfloat16(inv);
    Bc[k * 512 + 256 + d] = __float2bfloat16(-2.f * mc * inv);
    float s1 = l, s2 = mc * mc * inv;
    #pragma unroll
    for (int sh = 32; sh; sh >>= 1) { s1 += __shfl_xor(s1, sh); s2 += __shfl_xor(s2, sh); }
    int lane = tid & 63, wv = tid >> 6;
    if (lane == 0) { red1[wv] = s1; red2[wv] = s2; }
    __syncthreads();
    if (tid == 0) {
      float t1 = red1[0] + red1[1] + red1[2] + red1[3];
      float t2 = red2[0] + red2[1] + red2[2] + red2[3];
      c3k[k] = t2;
      ckk[k] = t1 + t2;
    }
  }
}

// ---- kernel 1: mega-fused (everything after prep) --------------------------
// 512 blocks x 512 thr (8 waves, 2 blocks/CU). Block owns 16 b-rows.
// Phase 1: K-chunked (8 x 32): W-chunk [512][32] staged via global_load_lds
//   into linear LDS; wave w owns n-frags (pl*256 + w*32 + dp*16), 4 MFMA/chunk.
//   x converted to bf16 ONCE into Axb LDS; eps prefetched to regs.
// Epilogue 1: z -> d_out; bf16 [z^2|z]/[sq+mu^2|mu] -> AcT/AqT (LDS).
// Phase 2: cluster GEMMs, wave w = 64-feature K-slice; LDS reduce; softmax.
// Tail: part write + last-block global reduce (replaces final_k node).
__global__ __launch_bounds__(512, 4) void mega_k(const float* __restrict__ xf,
                                                 const __hip_bfloat16* __restrict__ wbf,
                                                 const float* __restrict__ bmu,
                                                 const float* __restrict__ bsigv,
                                                 const float* __restrict__ eps,
                                                 const __hip_bfloat16* __restrict__ Bc,
                                                 const float* __restrict__ c3k,
                                                 const float* __restrict__ ckk,
                                                 float* __restrict__ zout,
                                                 float* __restrict__ part,
                                                 int* __restrict__ cnt,
                                                 float* __restrict__ out) {
  __shared__ __align__(16) unsigned short AcT[16][520];
  __shared__ __align__(16) unsigned short AqT[16][520];
  __shared__ __align__(16) unsigned short Axb[16][264];
  // union: phase1 = Bst [512][32] bf16 (32768 B); phase2 = sW (33792 B) + piP + gSum
  __shared__ __align__(16) char uniBuf[33928];
  __shared__ int lastFlag;
  float (*sW)[2][16][33] = (float (*)[2][16][33])uniBuf;
  float* piP  = (float*)(uniBuf + 33792);
  float* gSum = (float*)(uniBuf + 33920);

  const int tid = threadIdx.x, lane = tid & 63, w = tid >> 6;
  const int lrow = lane & 15, q = lane >> 4;
  const int m0 = blockIdx.x * 16;

  if (tid < NK) piP[tid] = 0.f;           // disjoint from Bst region (offset>32768)
  if (tid == NK) *gSum = 0.f;

  // eps prefetch (latency hides under first staging barrier)
  float epv[2][4];
  #pragma unroll
  for (int dp = 0; dp < 2; ++dp) {
    const int d = w * 32 + dp * 16 + lrow;
    #pragma unroll
    for (int j = 0; j < 4; ++j)
      epv[dp][j] = eps[(size_t)(m0 + q * 4 + j) * ND + d];
  }

  // stage x -> bf16 Axb (once): thread t covers row t>>5, cols (t&31)*8..+8
  {
    const int r = tid >> 5, c0 = (tid & 31) * 8;
    const float* xr = xf + (size_t)(m0 + r) * ND + c0;
    float4 lo = *reinterpret_cast<const float4*>(xr);
    float4 hi = *reinterpret_cast<const float4*>(xr + 4);
    *reinterpret_cast<short8*>(&Axb[r][c0]) = pack_bf16x8(lo, hi);
  }

  // ---------------- phase 1: GEMM1, K-chunked with LDS-staged W ------------
  f32x4 acc[2][2];   // [dp][plane]
  acc[0][0] = acc[0][1] = acc[1][0] = acc[1][1] = (f32x4){0.f, 0.f, 0.f, 0.f};

  for (int ck = 0; ck < 8; ++ck) {
    const int k0 = ck * 32;
    __syncthreads();   // Bst free (prev chunk's reads done)
    // stage W chunk [512 n][32 k] -> Bst linear: slot s (16B) = n*4 + koff
    #pragma unroll
    for (int c = 0; c < 4; ++c) {
      const int s = c * 512 + tid;
      const __hip_bfloat16* gp = wbf + (size_t)(s >> 2) * ND + k0 + (s & 3) * 8;
      char* lp = uniBuf + (size_t)(c * 512 + w * 64) * 16;   // wave-uniform base
      __builtin_amdgcn_global_load_lds(
          (const __attribute__((address_space(1))) unsigned int*)gp,
          (__attribute__((address_space(3))) unsigned int*)lp, 16, 0, 0);
    }
    __syncthreads();   // staging (and, iter0, Axb) visible
    short8 aF = *reinterpret_cast<const short8*>(&Axb[lrow][k0 + q * 8]);
    #pragma unroll
    for (int dp = 0; dp < 2; ++dp)
      #pragma unroll
      for (int pl = 0; pl < 2; ++pl) {
        const int nrow = pl * 256 + w * 32 + dp * 16 + lrow;
        short8 bF = *reinterpret_cast<const short8*>(uniBuf + (size_t)nrow * 64 + q * 16);
        acc[dp][pl] = mfma_bf16(aF, bF, acc[dp][pl]);
      }
  }

  // ---------------- epilogue 1: z + LDS deposit ----------------
  #pragma unroll
  for (int dp = 0; dp < 2; ++dp) {
    const int d = w * 32 + dp * 16 + lrow;
    const float bm = bmu[d], bs = bsigv[d];
    #pragma unroll
    for (int j = 0; j < 4; ++j) {
      const int bl = q * 4 + j;
      const int b = m0 + bl;
      float muv = acc[dp][0][j] + bm;
      float lsv = acc[dp][1][j] + bs;
      float sq  = __expf(lsv);
      float zv  = muv + sqrtf(sq) * epv[dp][j];
      zout[(size_t)b * ND + d] = zv;
      AcT[bl][d]       = f2bf(zv * zv);
      AcT[bl][256 + d] = f2bf(zv);
      AqT[bl][d]       = f2bf(sq + muv * muv);
      AqT[bl][256 + d] = f2bf(muv);
    }
  }
  __syncthreads();   // AcT/AqT ready; Bst dead -> sW region usable

  // ---------------- phase 2: cluster GEMMs (64-feature slice per wave) ------
  f32x4 cL[2], cQ[2];
  cL[0] = cL[1] = cQ[0] = cQ[1] = (f32x4){0.f, 0.f, 0.f, 0.f};
  #pragma unroll
  for (int ks = 0; ks < 2; ++ks) {
    const int kc = w * 64 + ks * 32 + q * 8;
    short8 ac = *reinterpret_cast<const short8*>(&AcT[lrow][kc]);
    short8 aq = *reinterpret_cast<const short8*>(&AqT[lrow][kc]);
    short8 b0 = *reinterpret_cast<const short8*>(Bc + (size_t)lrow * 512 + kc);
    short8 b1 = *reinterpret_cast<const short8*>(Bc + (size_t)(16 + lrow) * 512 + kc);
    cL[0] = mfma_bf16(ac, b0, cL[0]);
    cL[1] = mfma_bf16(ac, b1, cL[1]);
    cQ[0] = mfma_bf16(aq, b0, cQ[0]);
    cQ[1] = mfma_bf16(aq, b1, cQ[1]);
  }
  #pragma unroll
  for (int nfk = 0; nfk < 2; ++nfk)
    #pragma unroll
    for (int j = 0; j < 4; ++j) {
      sW[w][0][q * 4 + j][nfk * 16 + lrow] = cL[nfk][j];
      sW[w][1][q * 4 + j][nfk * 16 + lrow] = cQ[nfk][j];
    }
  __syncthreads();

  // ---------------- epilogue 2: softmax + loss partials ----------------
  if (tid < 256) {
    const int b = tid >> 4, kk = tid & 15;
    float L0 = 0.f, L1 = 0.f, Q0 = 0.f, Q1 = 0.f;
    #pragma unroll
    for (int ww = 0; ww < 8; ++ww) {
      L0 += sW[ww][0][b][kk];      L1 += sW[ww][0][b][kk + 16];
      Q0 += sW[ww][1][b][kk];      Q1 += sW[ww][1][b][kk + 16];
    }
    float l0 = -(L0 + c3k[kk]);
    float l1 = -(L1 + c3k[kk + 16]);
    float mx = fmaxf(l0, l1);
    #pragma unroll
    for (int s = 8; s; s >>= 1) mx = fmaxf(mx, __shfl_xor(mx, s));
    float p0 = __expf(l0 - mx), p1 = __expf(l1 - mx);
    float ps = p0 + p1;
    #pragma unroll
    for (int s = 8; s; s >>= 1) ps += __shfl_xor(ps, s);
    float pi0 = p0 / ps + 1e-10f;
    float pi1 = p1 / ps + 1e-10f;
    float g = pi0 * (Q0 + ckk[kk]) + pi1 * (Q1 + ckk[kk + 16]);
    #pragma unroll
    for (int s = 8; s; s >>= 1) g += __shfl_xor(g, s);
    atomicAdd(&piP[kk], pi0);
    atomicAdd(&piP[kk + 16], pi1);
    if (kk == 0) atomicAdd(gSum, g);
  }
  __syncthreads();
  if (tid < NK)  part[(size_t)tid * 512 + blockIdx.x] = piP[tid];
  if (tid == NK) part[(size_t)NK * 512 + blockIdx.x] = 0.5f * (*gSum);

  // ---------------- tail: last block reduces part -> out ----------------
  __threadfence();     // release our part writes (device scope, cross-XCD)
  __syncthreads();
  if (tid == 0) lastFlag = (atomicAdd(cnt, 1) == (int)gridDim.x - 1);
  __syncthreads();
  if (!lastFlag) return;
  __threadfence();     // acquire: invalidate stale caches before reading part
  float* redF = (float*)uniBuf;   // [33][8], overlays dead sW
  if (tid < 264) {
    const int c = tid >> 3, sg = tid & 7;
    const float4* p4 = reinterpret_cast<const float4*>(part + (size_t)c * 512 + sg * 64);
    float s = 0.f;
    #pragma unroll 4
    for (int i = 0; i < 16; ++i) {
      float4 v = p4[i];
      s += v.x + v.y + v.z + v.w;
    }
    redF[c * 8 + sg] = s;
  }
  __syncthreads();
  if (tid < 33) {
    float s = 0.f;
    #pragma unroll
    for (int sg = 0; sg < 8; ++sg) s += redF[tid * 8 + sg];
    if (tid == 32) {
      out[NB * ND] = s;                       // batch_gaussian_loss
    } else {
      float mk = s / (float)NB;
      float t = mk * logf(mk);
      #pragma unroll
      for (int sh = 16; sh; sh >>= 1) t += __shfl_xor(t, sh);
      if (tid == 0) out[NB * ND + 1] = t / (float)NK;   // batch_uniform_loss
    }
  }
}

extern "C" void kernel_launch(void* const* d_in, const int* in_sizes, int n_in,
                              void* d_out, int out_size, void* d_ws, size_t ws_size,
                              hipStream_t stream) {
  const float* x    = (const float*)d_in[0];
  const float* eps  = (const float*)d_in[1];
  const float* wmu  = (const float*)d_in[2];
  const float* bmu  = (const float*)d_in[3];
  const float* wsig = (const float*)d_in[4];
  const float* bsig = (const float*)d_in[5];
  const float* mu_c = (const float*)d_in[6];
  const float* lsc  = (const float*)d_in[7];
  float* out = (float*)d_out;

  char* ws = (char*)d_ws;
  __hip_bfloat16* wbf = (__hip_bfloat16*)ws;                      // 256 KiB
  __hip_bfloat16* Bc  = (__hip_bfloat16*)(ws + (256u << 10));     // 32 KiB
  float* c3k  = (float*)(ws + (288u << 10));                      // 128 B
  float* ckk  = (float*)(ws + (288u << 10) + 256u);               // 128 B
  float* part = (float*)(ws + (288u << 10) + 512u);               // 66 KiB
  int*   cnt  = (int*)(ws + (288u << 10) + 512u + 67584u);        // 4 B

  prep_k<<<544, 256, 0, stream>>>(wmu, wsig, wbf, mu_c, lsc, Bc, c3k, ckk, cnt);
  mega_k<<<512, 512, 0, stream>>>(x, wbf, bmu, bsig, eps, Bc, c3k, ckk, out, part, cnt, out);
}

// Round 7
// 53.109 us; speedup vs baseline: 1.8725x; 1.8725x over previous
//
#include <hip/hip_runtime.h>
#include <hip/hip_bf16.h>

typedef __attribute__((ext_vector_type(4))) float f32x4;
typedef __attribute__((ext_vector_type(8))) short short8;

#define NB 8192
#define ND 256
#define NK 32
#define PADF 520  // AcT/AqT row stride (ushort): 1040B, 16B-aligned

static __device__ __forceinline__ unsigned short f2bf(float f) {
  return __builtin_bit_cast(unsigned short, __float2bfloat16(f));
}

static __device__ __forceinline__ f32x4 mfma_bf16(short8 a, short8 b, f32x4 c) {
  return __builtin_amdgcn_mfma_f32_16x16x32_bf16(a, b, c, 0, 0, 0);
}

static __device__ __forceinline__ short8 pack_bf16x8(float4 lo, float4 hi) {
  short8 r;
  r[0] = (short)f2bf(lo.x); r[1] = (short)f2bf(lo.y);
  r[2] = (short)f2bf(lo.z); r[3] = (short)f2bf(lo.w);
  r[4] = (short)f2bf(hi.x); r[5] = (short)f2bf(hi.y);
  r[6] = (short)f2bf(hi.z); r[7] = (short)f2bf(hi.w);
  return r;
}

// ---- kernel 0: small prep ---------------------------------------------------
// blocks [0,512)   : Wcat = [W_mu; W_sig] -> bf16 [512][256]
// blocks [512,544) : Bc bf16 [32][512]; c3k[k]; ckk[k]; block 512 zeroes cnt
__global__ __launch_bounds__(256) void prep_k(const float* __restrict__ wmu,
                                              const float* __restrict__ wsig,
                                              __hip_bfloat16* __restrict__ wb,
                                              const float* __restrict__ mu_c,
                                              const float* __restrict__ lsc,
                                              __hip_bfloat16* __restrict__ Bc,
                                              float* __restrict__ c3k,
                                              float* __restrict__ ckk,
                                              int* __restrict__ cnt) {
  __shared__ float red1[4], red2[4];
  const int blk = blockIdx.x, tid = threadIdx.x;
  if (blk < 512) {
    int i = blk * 256 + tid;
    float v = (i < 65536) ? wmu[i] : wsig[i - 65536];
    wb[i] = __float2bfloat16(v);
  } else {
    if (blk == 512 && tid == 0) *cnt = 0;
    int k = blk - 512;
    int d = tid;
    float l = lsc[k * ND + d];
    float inv = __expf(-l);
    float mc = mu_c[k * ND + d];
    Bc[k * 512 + d]       = __float2bfloat16(inv);
    Bc[k * 512 + 256 + d] = __float2bfloat16(-2.f * mc * inv);
    float s1 = l, s2 = mc * mc * inv;
    #pragma unroll
    for (int sh = 32; sh; sh >>= 1) { s1 += __shfl_xor(s1, sh); s2 += __shfl_xor(s2, sh); }
    int lane = tid & 63, wv = tid >> 6;
    if (lane == 0) { red1[wv] = s1; red2[wv] = s2; }
    __syncthreads();
    if (tid == 0) {
      float t1 = red1[0] + red1[1] + red1[2] + red1[3];
      float t2 = red2[0] + red2[1] + red2[2] + red2[3];
      c3k[k] = t2;
      ckk[k] = t1 + t2;
    }
  }
}

// ---- kernel 1: mega-fused (R5-proven body + last-block tail) ---------------
// 512 blocks x 256 thr (4 waves), 3 blocks/CU. Block owns 16 b-rows.
// Phase 1 (GEMM1): wave w owns d-slice [w*64, w*64+64), mu & sig planes.
//   A: x read DIRECT as f32, converted to bf16 in-register.
//   B: Wcat bf16 direct from global (L2-hot). No LDS, no phase-1 barriers.
// Epilogue 1: z -> d_out; bf16 [z^2|z]/[sq+mu^2|mu] -> AcT/AqT (LDS).
// Phase 2: cluster GEMMs (wave w = 128-feature K-slice); LDS reduce; softmax.
// Tail: part via agent-scope atomics; last block reduces -> out (no final_k).
__global__ __launch_bounds__(256, 3) void mega_k(const float* __restrict__ xf,
                                                 const __hip_bfloat16* __restrict__ wbf,
                                                 const float* __restrict__ bmu,
                                                 const float* __restrict__ bsigv,
                                                 const float* __restrict__ eps,
                                                 const __hip_bfloat16* __restrict__ Bc,
                                                 const float* __restrict__ c3k,
                                                 const float* __restrict__ ckk,
                                                 float* __restrict__ zout,
                                                 float* __restrict__ part,
                                                 int* __restrict__ cnt,
                                                 float* __restrict__ out) {
  __shared__ __align__(16) unsigned short AcT[16][PADF];
  __shared__ __align__(16) unsigned short AqT[16][PADF];
  __shared__ float sW[4][2][16][33];
  __shared__ float piP[NK];
  __shared__ float gSum;
  __shared__ float redF[33 * 8];
  __shared__ int lastDone;

  const int tid = threadIdx.x, lane = tid & 63, w = tid >> 6;
  const int lrow = lane & 15, q = lane >> 4;
  const int m0 = blockIdx.x * 16;

  if (tid < NK) piP[tid] = 0.f;
  if (tid == 0) gSum = 0.f;

  // ---------------- phase 1: GEMM1 (direct-global operands) ----------------
  f32x4 acc[4][2];
  #pragma unroll
  for (int a = 0; a < 4; ++a) { acc[a][0] = (f32x4){0,0,0,0}; acc[a][1] = (f32x4){0,0,0,0}; }

  const float* aB = xf + (size_t)(m0 + lrow) * ND + q * 8;
  const __hip_bfloat16* bB[8];
  #pragma unroll
  for (int nf = 0; nf < 8; ++nf) {
    int wrow = (nf & 1) * 256 + w * 64 + (nf >> 1) * 16 + lrow;
    bB[nf] = wbf + (size_t)wrow * ND + q * 8;
  }

  #pragma unroll
  for (int ks = 0; ks < 8; ++ks) {
    const int kc = ks * 32;
    float4 alo = *reinterpret_cast<const float4*>(aB + kc);
    float4 ahi = *reinterpret_cast<const float4*>(aB + kc + 4);
    short8 a = pack_bf16x8(alo, ahi);
    #pragma unroll
    for (int nf = 0; nf < 8; ++nf) {
      short8 b = *reinterpret_cast<const short8*>(bB[nf] + kc);
      acc[nf >> 1][nf & 1] = mfma_bf16(a, b, acc[nf >> 1][nf & 1]);
    }
  }

  // ---------------- epilogue 1: z + LDS deposit ----------------
  #pragma unroll
  for (int dp = 0; dp < 4; ++dp) {
    const int d = w * 64 + dp * 16 + lrow;
    const float bm = bmu[d], bs = bsigv[d];
    #pragma unroll
    for (int j = 0; j < 4; ++j) {
      const int bl = q * 4 + j;
      const int b = m0 + bl;
      float muv = acc[dp][0][j] + bm;
      float lsv = acc[dp][1][j] + bs;
      float sq  = __expf(lsv);
      float e   = eps[(size_t)b * ND + d];
      float zv  = muv + sqrtf(sq) * e;
      zout[(size_t)b * ND + d] = zv;
      AcT[bl][d]       = f2bf(zv * zv);
      AcT[bl][256 + d] = f2bf(zv);
      AqT[bl][d]       = f2bf(sq + muv * muv);
      AqT[bl][256 + d] = f2bf(muv);
    }
  }
  __syncthreads();

  // ---------------- phase 2: cluster GEMMs (128-feature slice per wave) -----
  f32x4 cL[2], cQ[2];
  cL[0] = cL[1] = cQ[0] = cQ[1] = (f32x4){0,0,0,0};
  const int f0 = w * 128;
  #pragma unroll
  for (int ks = 0; ks < 4; ++ks) {
    const int kc = f0 + ks * 32 + q * 8;
    short8 ac = *reinterpret_cast<const short8*>(&AcT[lrow][kc]);
    short8 aq = *reinterpret_cast<const short8*>(&AqT[lrow][kc]);
    short8 b0 = *reinterpret_cast<const short8*>(Bc + (size_t)lrow * 512 + kc);
    short8 b1 = *reinterpret_cast<const short8*>(Bc + (size_t)(16 + lrow) * 512 + kc);
    cL[0] = mfma_bf16(ac, b0, cL[0]);
    cL[1] = mfma_bf16(ac, b1, cL[1]);
    cQ[0] = mfma_bf16(aq, b0, cQ[0]);
    cQ[1] = mfma_bf16(aq, b1, cQ[1]);
  }
  #pragma unroll
  for (int nfk = 0; nfk < 2; ++nfk)
    #pragma unroll
    for (int j = 0; j < 4; ++j) {
      sW[w][0][q * 4 + j][nfk * 16 + lrow] = cL[nfk][j];
      sW[w][1][q * 4 + j][nfk * 16 + lrow] = cQ[nfk][j];
    }
  __syncthreads();

  // ---------------- epilogue 2: softmax + loss partials ----------------
  {
    const int b = tid >> 4, kk = tid & 15;
    float L0 = sW[0][0][b][kk]      + sW[1][0][b][kk]      + sW[2][0][b][kk]      + sW[3][0][b][kk];
    float L1 = sW[0][0][b][kk + 16] + sW[1][0][b][kk + 16] + sW[2][0][b][kk + 16] + sW[3][0][b][kk + 16];
    float Q0 = sW[0][1][b][kk]      + sW[1][1][b][kk]      + sW[2][1][b][kk]      + sW[3][1][b][kk];
    float Q1 = sW[0][1][b][kk + 16] + sW[1][1][b][kk + 16] + sW[2][1][b][kk + 16] + sW[3][1][b][kk + 16];
    float l0 = -(L0 + c3k[kk]);
    float l1 = -(L1 + c3k[kk + 16]);
    float mx = fmaxf(l0, l1);
    #pragma unroll
    for (int s = 8; s; s >>= 1) mx = fmaxf(mx, __shfl_xor(mx, s));
    float p0 = __expf(l0 - mx), p1 = __expf(l1 - mx);
    float ps = p0 + p1;
    #pragma unroll
    for (int s = 8; s; s >>= 1) ps += __shfl_xor(ps, s);
    float pi0 = p0 / ps + 1e-10f;
    float pi1 = p1 / ps + 1e-10f;
    float g = pi0 * (Q0 + ckk[kk]) + pi1 * (Q1 + ckk[kk + 16]);
    #pragma unroll
    for (int s = 8; s; s >>= 1) g += __shfl_xor(g, s);
    atomicAdd(&piP[kk], pi0);
    atomicAdd(&piP[kk + 16], pi1);
    if (kk == 0) atomicAdd(&gSum, g);
  }
  __syncthreads();

  // ---------------- tail: agent-scope part writes + last-block reduce -------
  if (tid < NK)
    __hip_atomic_store(&part[(size_t)tid * 512 + blockIdx.x], piP[tid],
                       __ATOMIC_RELAXED, __HIP_MEMORY_SCOPE_AGENT);
  if (tid == NK)
    __hip_atomic_store(&part[(size_t)NK * 512 + blockIdx.x], 0.5f * gSum,
                       __ATOMIC_RELAXED, __HIP_MEMORY_SCOPE_AGENT);
  if (tid == 0) {
    int old = __hip_atomic_fetch_add(cnt, 1, __ATOMIC_ACQ_REL, __HIP_MEMORY_SCOPE_AGENT);
    lastDone = (old == 511);
  }
  __syncthreads();
  if (!lastDone) return;

  // last block: fixed-order deterministic reduce of part[33][512]
  for (int c = (tid >> 3); c < 33; c += 32) {
    const int sg = tid & 7;
    const float* pp = part + (size_t)c * 512 + sg * 64;
    float s = 0.f;
    #pragma unroll 8
    for (int i = 0; i < 64; ++i)
      s += __hip_atomic_load(&pp[i], __ATOMIC_RELAXED, __HIP_MEMORY_SCOPE_AGENT);
    redF[c * 8 + (tid & 7)] = s;
  }
  __syncthreads();
  if (tid < 33) {
    float s = 0.f;
    #pragma unroll
    for (int sg = 0; sg < 8; ++sg) s += redF[tid * 8 + sg];
    if (tid == 32) {
      out[NB * ND] = s;                       // batch_gaussian_loss
    } else {
      float mk = s / (float)NB;
      float t = mk * logf(mk);
      #pragma unroll
      for (int sh = 16; sh; sh >>= 1) t += __shfl_xor(t, sh);
      if (tid == 0) out[NB * ND + 1] = t / (float)NK;   // batch_uniform_loss
    }
  }
}

extern "C" void kernel_launch(void* const* d_in, const int* in_sizes, int n_in,
                              void* d_out, int out_size, void* d_ws, size_t ws_size,
                              hipStream_t stream) {
  const float* x    = (const float*)d_in[0];
  const float* eps  = (const float*)d_in[1];
  const float* wmu  = (const float*)d_in[2];
  const float* bmu  = (const float*)d_in[3];
  const float* wsig = (const float*)d_in[4];
  const float* bsig = (const float*)d_in[5];
  const float* mu_c = (const float*)d_in[6];
  const float* lsc  = (const float*)d_in[7];
  float* out = (float*)d_out;

  char* ws = (char*)d_ws;
  __hip_bfloat16* wbf = (__hip_bfloat16*)ws;                      // 256 KiB
  __hip_bfloat16* Bc  = (__hip_bfloat16*)(ws + (256u << 10));     // 32 KiB
  float* c3k  = (float*)(ws + (288u << 10));                      // 128 B
  float* ckk  = (float*)(ws + (288u << 10) + 256u);               // 128 B
  float* part = (float*)(ws + (288u << 10) + 512u);               // 66 KiB
  int*   cnt  = (int*)(ws + (288u << 10) + 512u + 67584u);        // 4 B

  prep_k<<<544, 256, 0, stream>>>(wmu, wsig, wbf, mu_c, lsc, Bc, c3k, ckk, cnt);
  mega_k<<<512, 256, 0, stream>>>(x, wbf, bmu, bsig, eps, Bc, c3k, ckk, out, part, cnt, out);
}

// Round 8
// 35.582 us; speedup vs baseline: 2.7949x; 1.4926x over previous
//
#include <hip/hip_runtime.h>
#include <hip/hip_bf16.h>

typedef __attribute__((ext_vector_type(4))) float f32x4;
typedef __attribute__((ext_vector_type(8))) short short8;

#define NB 8192
#define ND 256
#define NK 32
#define PADF 520  // AcT/AqT row stride (ushort): 1040B; 260 words -> bank stride 4, 2-way (free)

static __device__ __forceinline__ unsigned short f2bf(float f) {
  return __builtin_bit_cast(unsigned short, __float2bfloat16(f));
}

static __device__ __forceinline__ f32x4 mfma_bf16(short8 a, short8 b, f32x4 c) {
  return __builtin_amdgcn_mfma_f32_16x16x32_bf16(a, b, c, 0, 0, 0);
}

static __device__ __forceinline__ short8 pack_bf16x8(float4 lo, float4 hi) {
  short8 r;
  r[0] = (short)f2bf(lo.x); r[1] = (short)f2bf(lo.y);
  r[2] = (short)f2bf(lo.z); r[3] = (short)f2bf(lo.w);
  r[4] = (short)f2bf(hi.x); r[5] = (short)f2bf(hi.y);
  r[6] = (short)f2bf(hi.z); r[7] = (short)f2bf(hi.w);
  return r;
}

// ---- kernel 0: small prep ---------------------------------------------------
// blocks [0,512)   : Wcat = [W_mu; W_sig] -> bf16 [512][256]
// blocks [512,544) : Bc bf16 [32][512]; c3k[k]; ckk[k]
__global__ __launch_bounds__(256) void prep_k(const float* __restrict__ wmu,
                                              const float* __restrict__ wsig,
                                              __hip_bfloat16* __restrict__ wb,
                                              const float* __restrict__ mu_c,
                                              const float* __restrict__ lsc,
                                              __hip_bfloat16* __restrict__ Bc,
                                              float* __restrict__ c3k,
                                              float* __restrict__ ckk) {
  __shared__ float red1[4], red2[4];
  const int blk = blockIdx.x, tid = threadIdx.x;
  if (blk < 512) {
    int i = blk * 256 + tid;
    float v = (i < 65536) ? wmu[i] : wsig[i - 65536];
    wb[i] = __float2bfloat16(v);
  } else {
    int k = blk - 512;
    int d = tid;
    float l = lsc[k * ND + d];
    float inv = __expf(-l);
    float mc = mu_c[k * ND + d];
    Bc[k * 512 + d]       = __float2bfloat16(inv);
    Bc[k * 512 + 256 + d] = __float2bfloat16(-2.f * mc * inv);
    float s1 = l, s2 = mc * mc * inv;
    #pragma unroll
    for (int sh = 32; sh; sh >>= 1) { s1 += __shfl_xor(s1, sh); s2 += __shfl_xor(s2, sh); }
    int lane = tid & 63, wv = tid >> 6;
    if (lane == 0) { red1[wv] = s1; red2[wv] = s2; }
    __syncthreads();
    if (tid == 0) {
      float t1 = red1[0] + red1[1] + red1[2] + red1[3];
      float t2 = red2[0] + red2[1] + red2[2] + red2[3];
      c3k[k] = t2;
      ckk[k] = t1 + t2;
    }
  }
}

// ---- kernel 1: mega (register-blocked GEMM1 rounds + fused cluster) --------
// 512 blocks x 256 thr (4 waves), 3 blocks/CU (LDS 50.3KB). Block = 16 b-rows.
// Stage: x[16][256] -> bf16 Axb (LDS). Each wave hoists its 8 A-frags (32 VGPR).
// Phase 1: 4 rounds; round r: wave w owns d-slice [(r*4+w)*16, +16):
//   16 coalesced W loads (reg-resident, freed per round) + 16 MFMAs +
//   per-round epilogue (z -> d_out, bf16 [z^2|z]/[sq+mu^2|mu] -> AcT/AqT).
// Phase 2: cluster GEMMs (wave w = 128-feature slice), sW reduce (overlays
//   dead Axb), 16-lane softmax, part[33][512]. No cross-block tail.
__global__ __launch_bounds__(256, 3) void mega_k(const float* __restrict__ xf,
                                                 const __hip_bfloat16* __restrict__ wbf,
                                                 const float* __restrict__ bmu,
                                                 const float* __restrict__ bsigv,
                                                 const float* __restrict__ eps,
                                                 const __hip_bfloat16* __restrict__ Bc,
                                                 const float* __restrict__ c3k,
                                                 const float* __restrict__ ckk,
                                                 float* __restrict__ zout,
                                                 float* __restrict__ part) {
  __shared__ __align__(16) unsigned short AcT[16][PADF];
  __shared__ __align__(16) unsigned short AqT[16][PADF];
  __shared__ __align__(16) char uniBuf[16896];   // Axb [16][264] ushort | sW [4][2][16][33] f32
  __shared__ float piP[NK];
  __shared__ float gSum;
  unsigned short (*Axb)[264] = (unsigned short (*)[264])uniBuf;
  float (*sW)[2][16][33] = (float (*)[2][16][33])uniBuf;

  const int tid = threadIdx.x, lane = tid & 63, w = tid >> 6;
  const int lrow = lane & 15, q = lane >> 4;
  const int m0 = blockIdx.x * 16;

  if (tid < NK) piP[tid] = 0.f;
  if (tid == NK) gSum = 0.f;

  // ---- stage x -> bf16 Axb: thread t covers row t>>4, 16 cols from (t&15)*16
  {
    const int r = tid >> 4, c0 = (tid & 15) * 16;
    const float* xr = xf + (size_t)(m0 + r) * ND + c0;
    float4 a0 = *reinterpret_cast<const float4*>(xr);
    float4 a1 = *reinterpret_cast<const float4*>(xr + 4);
    float4 a2 = *reinterpret_cast<const float4*>(xr + 8);
    float4 a3 = *reinterpret_cast<const float4*>(xr + 12);
    *reinterpret_cast<short8*>(&Axb[r][c0])     = pack_bf16x8(a0, a1);
    *reinterpret_cast<short8*>(&Axb[r][c0 + 8]) = pack_bf16x8(a2, a3);
  }
  __syncthreads();

  // ---- hoisted A fragments (whole K=256, held for all rounds)
  short8 aF[8];
  #pragma unroll
  for (int kk = 0; kk < 8; ++kk)
    aF[kk] = *reinterpret_cast<const short8*>(&Axb[lrow][kk * 32 + q * 8]);

  // ---- phase 1: 4 rounds of (16 B loads + 16 MFMAs + epilogue)
  #pragma unroll
  for (int r = 0; r < 4; ++r) {
    const int d0 = (r * 4 + w) * 16;
    const __hip_bfloat16* bMuP = wbf + (size_t)(d0 + lrow) * ND + q * 8;
    const __hip_bfloat16* bSgP = bMuP + (size_t)256 * ND;
    f32x4 aM = (f32x4){0.f, 0.f, 0.f, 0.f};
    f32x4 aS = (f32x4){0.f, 0.f, 0.f, 0.f};
    #pragma unroll
    for (int kk = 0; kk < 8; ++kk) {
      short8 bM = *reinterpret_cast<const short8*>(bMuP + kk * 32);
      short8 bS = *reinterpret_cast<const short8*>(bSgP + kk * 32);
      aM = mfma_bf16(aF[kk], bM, aM);
      aS = mfma_bf16(aF[kk], bS, aS);
    }
    // per-round epilogue: C/D layout col(lrow)->d, row(q*4+j)->b
    const int d = d0 + lrow;
    const float bm = bmu[d], bs = bsigv[d];
    #pragma unroll
    for (int j = 0; j < 4; ++j) {
      const int bl = q * 4 + j;
      const int b = m0 + bl;
      float muv = aM[j] + bm;
      float lsv = aS[j] + bs;
      float sq  = __expf(lsv);
      float e   = eps[(size_t)b * ND + d];
      float zv  = muv + sqrtf(sq) * e;
      zout[(size_t)b * ND + d] = zv;
      AcT[bl][d]       = f2bf(zv * zv);
      AcT[bl][256 + d] = f2bf(zv);
      AqT[bl][d]       = f2bf(sq + muv * muv);
      AqT[bl][256 + d] = f2bf(muv);
    }
  }
  __syncthreads();   // AcT/AqT ready; Axb dead -> sW region usable

  // ---- phase 2: cluster GEMMs (128-feature slice per wave)
  f32x4 cL[2], cQ[2];
  cL[0] = cL[1] = cQ[0] = cQ[1] = (f32x4){0.f, 0.f, 0.f, 0.f};
  const int f0 = w * 128;
  #pragma unroll
  for (int ks = 0; ks < 4; ++ks) {
    const int kc = f0 + ks * 32 + q * 8;
    short8 ac = *reinterpret_cast<const short8*>(&AcT[lrow][kc]);
    short8 aq = *reinterpret_cast<const short8*>(&AqT[lrow][kc]);
    short8 b0 = *reinterpret_cast<const short8*>(Bc + (size_t)lrow * 512 + kc);
    short8 b1 = *reinterpret_cast<const short8*>(Bc + (size_t)(16 + lrow) * 512 + kc);
    cL[0] = mfma_bf16(ac, b0, cL[0]);
    cL[1] = mfma_bf16(ac, b1, cL[1]);
    cQ[0] = mfma_bf16(aq, b0, cQ[0]);
    cQ[1] = mfma_bf16(aq, b1, cQ[1]);
  }
  #pragma unroll
  for (int nfk = 0; nfk < 2; ++nfk)
    #pragma unroll
    for (int j = 0; j < 4; ++j) {
      sW[w][0][q * 4 + j][nfk * 16 + lrow] = cL[nfk][j];
      sW[w][1][q * 4 + j][nfk * 16 + lrow] = cQ[nfk][j];
    }
  __syncthreads();

  // ---- epilogue 2: softmax + loss partials
  {
    const int b = tid >> 4, kk = tid & 15;
    float L0 = sW[0][0][b][kk]      + sW[1][0][b][kk]      + sW[2][0][b][kk]      + sW[3][0][b][kk];
    float L1 = sW[0][0][b][kk + 16] + sW[1][0][b][kk + 16] + sW[2][0][b][kk + 16] + sW[3][0][b][kk + 16];
    float Q0 = sW[0][1][b][kk]      + sW[1][1][b][kk]      + sW[2][1][b][kk]      + sW[3][1][b][kk];
    float Q1 = sW[0][1][b][kk + 16] + sW[1][1][b][kk + 16] + sW[2][1][b][kk + 16] + sW[3][1][b][kk + 16];
    float l0 = -(L0 + c3k[kk]);
    float l1 = -(L1 + c3k[kk + 16]);
    float mx = fmaxf(l0, l1);
    #pragma unroll
    for (int s = 8; s; s >>= 1) mx = fmaxf(mx, __shfl_xor(mx, s));
    float p0 = __expf(l0 - mx), p1 = __expf(l1 - mx);
    float ps = p0 + p1;
    #pragma unroll
    for (int s = 8; s; s >>= 1) ps += __shfl_xor(ps, s);
    float pi0 = p0 / ps + 1e-10f;
    float pi1 = p1 / ps + 1e-10f;
    float g = pi0 * (Q0 + ckk[kk]) + pi1 * (Q1 + ckk[kk + 16]);
    #pragma unroll
    for (int s = 8; s; s >>= 1) g += __shfl_xor(g, s);
    atomicAdd(&piP[kk], pi0);
    atomicAdd(&piP[kk + 16], pi1);
    if (kk == 0) atomicAdd(&gSum, g);
  }
  __syncthreads();
  if (tid < NK)  part[(size_t)tid * 512 + blockIdx.x] = piP[tid];
  if (tid == NK) part[(size_t)NK * 512 + blockIdx.x] = 0.5f * gSum;
}

// ---- kernel 2: final reduce (part[33][512], float4 rows, 4-way wave split) -
__global__ __launch_bounds__(256) void final_k(const float* __restrict__ part,
                                               float* __restrict__ out) {
  __shared__ double red[4][33];
  const int tid = threadIdx.x, lane = tid & 63, wv = tid >> 6;
  if (lane < 33) {
    const float4* p4 = reinterpret_cast<const float4*>(part + (size_t)lane * 512);
    double acc = 0.0;
    for (int i = wv * 32; i < wv * 32 + 32; ++i) {
      float4 v = p4[i];
      acc += (double)v.x + (double)v.y + (double)v.z + (double)v.w;
    }
    red[wv][lane] = acc;
  }
  __syncthreads();
  if (tid >= 64) return;
  double s = (tid < 33) ? (red[0][tid] + red[1][tid] + red[2][tid] + red[3][tid]) : 0.0;
  if (tid == 32) out[NB * ND] = (float)s;            // batch_gaussian_loss
  double t = 0.0;
  if (tid < 32) { double mk = s / (double)NB; t = mk * log(mk); }
  #pragma unroll
  for (int sh = 16; sh; sh >>= 1) t += __shfl_xor(t, sh);
  if (tid == 0) out[NB * ND + 1] = (float)(t / (double)NK);
}

extern "C" void kernel_launch(void* const* d_in, const int* in_sizes, int n_in,
                              void* d_out, int out_size, void* d_ws, size_t ws_size,
                              hipStream_t stream) {
  const float* x    = (const float*)d_in[0];
  const float* eps  = (const float*)d_in[1];
  const float* wmu  = (const float*)d_in[2];
  const float* bmu  = (const float*)d_in[3];
  const float* wsig = (const float*)d_in[4];
  const float* bsig = (const float*)d_in[5];
  const float* mu_c = (const float*)d_in[6];
  const float* lsc  = (const float*)d_in[7];
  float* out = (float*)d_out;

  char* ws = (char*)d_ws;
  __hip_bfloat16* wbf = (__hip_bfloat16*)ws;                      // 256 KiB
  __hip_bfloat16* Bc  = (__hip_bfloat16*)(ws + (256u << 10));     // 32 KiB
  float* c3k  = (float*)(ws + (288u << 10));                      // 128 B
  float* ckk  = (float*)(ws + (288u << 10) + 256u);               // 128 B
  float* part = (float*)(ws + (288u << 10) + 512u);               // 66 KiB

  prep_k<<<544, 256, 0, stream>>>(wmu, wsig, wbf, mu_c, lsc, Bc, c3k, ckk);
  mega_k<<<512, 256, 0, stream>>>(x, wbf, bmu, bsig, eps, Bc, c3k, ckk, out, part);
  final_k<<<1, 256, 0, stream>>>(part, out);
}

// Round 9
// 26.176 us; speedup vs baseline: 3.7992x; 1.3593x over previous
//
#include <hip/hip_runtime.h>
#include <hip/hip_bf16.h>

typedef __attribute__((ext_vector_type(4))) float f32x4;
typedef __attribute__((ext_vector_type(8))) short short8;

#define NB 8192
#define ND 256
#define NK 32
#define PADF 520  // AcT/AqT row stride (ushort): 1040B; 260 words -> bank stride 4, 2-way (free)

static __device__ __forceinline__ unsigned short f2bf(float f) {
  return __builtin_bit_cast(unsigned short, __float2bfloat16(f));
}

static __device__ __forceinline__ f32x4 mfma_bf16(short8 a, short8 b, f32x4 c) {
  return __builtin_amdgcn_mfma_f32_16x16x32_bf16(a, b, c, 0, 0, 0);
}

static __device__ __forceinline__ short8 pack_bf16x8(float4 lo, float4 hi) {
  short8 r;
  r[0] = (short)f2bf(lo.x); r[1] = (short)f2bf(lo.y);
  r[2] = (short)f2bf(lo.z); r[3] = (short)f2bf(lo.w);
  r[4] = (short)f2bf(hi.x); r[5] = (short)f2bf(hi.y);
  r[6] = (short)f2bf(hi.z); r[7] = (short)f2bf(hi.w);
  return r;
}

// ---- kernel 0: prep with FRAGMENT-SWIZZLED outputs --------------------------
// Wsw: frag f = rb*8 + kb (rb: 16-row block of Wcat[512][256], kb: 32-k block)
//      Wsw[f*512 + l*8 + e] = Wcat[rb*16 + (l&15)][kb*32 + (l>>4)*8 + e]
//   -> one wave B-fragment load = contiguous 1KB (fully coalesced).
// Bcsw: frag f = rb*16 + kb (rb: 16-row block of Bc[32][512], kb: 32-col blk)
//      Bcsw[f*512 + l*8 + e] = Bc[rb*16 + (l&15)][kb*32 + (l>>4)*8 + e]
//   where Bc[k][c] = c<256 ? exp(-lsc[k,c]) : -2*mu_c[k,c-256]*exp(-lsc[k,c-256])
// blocks [0,512): Wsw.  blocks [512,544): Bcsw + c3k/ckk.
__global__ __launch_bounds__(256) void prep_k(const float* __restrict__ wmu,
                                              const float* __restrict__ wsig,
                                              __hip_bfloat16* __restrict__ wsw,
                                              const float* __restrict__ mu_c,
                                              const float* __restrict__ lsc,
                                              __hip_bfloat16* __restrict__ bcsw,
                                              float* __restrict__ c3k,
                                              float* __restrict__ ckk) {
  __shared__ float red1[4], red2[4];
  const int blk = blockIdx.x, tid = threadIdx.x;
  if (blk < 512) {
    int i = blk * 256 + tid;            // element index in Wsw
    int f = i >> 9, r = i & 511;
    int l = r >> 3, e = r & 7;
    int n = (f >> 3) * 16 + (l & 15);             // Wcat row
    int k = (f & 7) * 32 + ((l >> 4) << 3) + e;   // Wcat col
    float v = (n < 256) ? wmu[n * ND + k] : wsig[(n - 256) * ND + k];
    wsw[i] = __float2bfloat16(v);
  } else {
    int k = blk - 512;    // cluster index
    int d = tid;
    float l = lsc[k * ND + d];
    float inv = __expf(-l);
    float mc = mu_c[k * ND + d];
    const int rb = k >> 4, lrow = k & 15;
    // swizzled write positions for feature cols c1=d (inv) and c2=256+d (-2 mc inv)
    {
      int c = d;
      int kb = c >> 5, q = (c >> 3) & 3, e = c & 7;
      bcsw[(size_t)(rb * 16 + kb) * 512 + (q * 16 + lrow) * 8 + e] = __float2bfloat16(inv);
    }
    {
      int c = 256 + d;
      int kb = c >> 5, q = (c >> 3) & 3, e = c & 7;
      bcsw[(size_t)(rb * 16 + kb) * 512 + (q * 16 + lrow) * 8 + e] = __float2bfloat16(-2.f * mc * inv);
    }
    float s1 = l, s2 = mc * mc * inv;
    #pragma unroll
    for (int sh = 32; sh; sh >>= 1) { s1 += __shfl_xor(s1, sh); s2 += __shfl_xor(s2, sh); }
    int lane = tid & 63, wv = tid >> 6;
    if (lane == 0) { red1[wv] = s1; red2[wv] = s2; }
    __syncthreads();
    if (tid == 0) {
      float t1 = red1[0] + red1[1] + red1[2] + red1[3];
      float t2 = red2[0] + red2[1] + red2[2] + red2[3];
      c3k[k] = t2;
      ckk[k] = t1 + t2;
    }
  }
}

// ---- kernel 1: mega (R8 structure + coalesced swizzled B loads) ------------
// 512 blocks x 256 thr (4 waves), 2 blocks/CU. Block = 16 b-rows.
// Stage x -> bf16 Axb (LDS); wave hoists its 8 A-frags (32 VGPR).
// Phase 1: 4 rounds; round r: wave w owns d-slice [(r*4+w)*16, +16):
//   16 COALESCED 1KB frag loads from Wsw (batched: load-loop then MFMA-loop)
//   + 16 MFMAs + per-round epilogue (z -> out, bf16 rows -> AcT/AqT).
// Phase 2: cluster GEMMs (wave w = 128-feature slice; Bcsw frag loads
//   coalesced), sW reduce (overlays dead Axb), 16-lane softmax, part[33][512].
__global__ __launch_bounds__(256, 2) void mega_k(const float* __restrict__ xf,
                                                 const __hip_bfloat16* __restrict__ wsw,
                                                 const float* __restrict__ bmu,
                                                 const float* __restrict__ bsigv,
                                                 const float* __restrict__ eps,
                                                 const __hip_bfloat16* __restrict__ bcsw,
                                                 const float* __restrict__ c3k,
                                                 const float* __restrict__ ckk,
                                                 float* __restrict__ zout,
                                                 float* __restrict__ part) {
  __shared__ __align__(16) unsigned short AcT[16][PADF];
  __shared__ __align__(16) unsigned short AqT[16][PADF];
  __shared__ __align__(16) char uniBuf[16896];   // Axb [16][264] ushort | sW [4][2][16][33] f32
  __shared__ float piP[NK];
  __shared__ float gSum;
  unsigned short (*Axb)[264] = (unsigned short (*)[264])uniBuf;
  float (*sW)[2][16][33] = (float (*)[2][16][33])uniBuf;

  const int tid = threadIdx.x, lane = tid & 63, w = tid >> 6;
  const int lrow = lane & 15, q = lane >> 4;
  const int m0 = blockIdx.x * 16;

  if (tid < NK) piP[tid] = 0.f;
  if (tid == NK) gSum = 0.f;

  // ---- stage x -> bf16 Axb: thread t covers row t>>4, 16 cols from (t&15)*16
  {
    const int r = tid >> 4, c0 = (tid & 15) * 16;
    const float* xr = xf + (size_t)(m0 + r) * ND + c0;
    float4 a0 = *reinterpret_cast<const float4*>(xr);
    float4 a1 = *reinterpret_cast<const float4*>(xr + 4);
    float4 a2 = *reinterpret_cast<const float4*>(xr + 8);
    float4 a3 = *reinterpret_cast<const float4*>(xr + 12);
    *reinterpret_cast<short8*>(&Axb[r][c0])     = pack_bf16x8(a0, a1);
    *reinterpret_cast<short8*>(&Axb[r][c0 + 8]) = pack_bf16x8(a2, a3);
  }
  __syncthreads();

  // ---- hoisted A fragments (whole K=256, held for all rounds)
  short8 aF[8];
  #pragma unroll
  for (int kk = 0; kk < 8; ++kk)
    aF[kk] = *reinterpret_cast<const short8*>(&Axb[lrow][kk * 32 + q * 8]);

  // ---- phase 1: 4 rounds of (16 coalesced frag loads + 16 MFMAs + epilogue)
  #pragma unroll
  for (int r = 0; r < 4; ++r) {
    const int rb = r * 4 + w;                 // mu row-block; sig = 16 + rb
    const __hip_bfloat16* pM = wsw + (size_t)(rb * 8) * 512 + lane * 8;
    const __hip_bfloat16* pS = wsw + (size_t)((16 + rb) * 8) * 512 + lane * 8;
    short8 bM[8], bS[8];
    #pragma unroll
    for (int kk = 0; kk < 8; ++kk) {
      bM[kk] = *reinterpret_cast<const short8*>(pM + kk * 512);
      bS[kk] = *reinterpret_cast<const short8*>(pS + kk * 512);
    }
    f32x4 aM = (f32x4){0.f, 0.f, 0.f, 0.f};
    f32x4 aS = (f32x4){0.f, 0.f, 0.f, 0.f};
    #pragma unroll
    for (int kk = 0; kk < 8; ++kk) {
      aM = mfma_bf16(aF[kk], bM[kk], aM);
      aS = mfma_bf16(aF[kk], bS[kk], aS);
    }
    // per-round epilogue: C/D layout col(lrow)->d, row(q*4+j)->b
    const int d = rb * 16 + lrow;
    const float bm = bmu[d], bs = bsigv[d];
    #pragma unroll
    for (int j = 0; j < 4; ++j) {
      const int bl = q * 4 + j;
      const int b = m0 + bl;
      float muv = aM[j] + bm;
      float lsv = aS[j] + bs;
      float sq  = __expf(lsv);
      float e   = eps[(size_t)b * ND + d];
      float zv  = muv + sqrtf(sq) * e;
      zout[(size_t)b * ND + d] = zv;
      AcT[bl][d]       = f2bf(zv * zv);
      AcT[bl][256 + d] = f2bf(zv);
      AqT[bl][d]       = f2bf(sq + muv * muv);
      AqT[bl][256 + d] = f2bf(muv);
    }
  }
  __syncthreads();   // AcT/AqT ready; Axb dead -> sW region usable

  // ---- phase 2: cluster GEMMs (128-feature slice per wave, coalesced Bcsw)
  f32x4 cL[2], cQ[2];
  cL[0] = cL[1] = cQ[0] = cQ[1] = (f32x4){0.f, 0.f, 0.f, 0.f};
  {
    short8 b0v[4], b1v[4], acv[4], aqv[4];
    #pragma unroll
    for (int ks = 0; ks < 4; ++ks) {
      const int kb = w * 4 + ks;              // 32-col block index
      b0v[ks] = *reinterpret_cast<const short8*>(bcsw + (size_t)kb * 512 + lane * 8);
      b1v[ks] = *reinterpret_cast<const short8*>(bcsw + (size_t)(16 + kb) * 512 + lane * 8);
      const int kc = kb * 32 + q * 8;
      acv[ks] = *reinterpret_cast<const short8*>(&AcT[lrow][kc]);
      aqv[ks] = *reinterpret_cast<const short8*>(&AqT[lrow][kc]);
    }
    #pragma unroll
    for (int ks = 0; ks < 4; ++ks) {
      cL[0] = mfma_bf16(acv[ks], b0v[ks], cL[0]);
      cL[1] = mfma_bf16(acv[ks], b1v[ks], cL[1]);
      cQ[0] = mfma_bf16(aqv[ks], b0v[ks], cQ[0]);
      cQ[1] = mfma_bf16(aqv[ks], b1v[ks], cQ[1]);
    }
  }
  #pragma unroll
  for (int nfk = 0; nfk < 2; ++nfk)
    #pragma unroll
    for (int j = 0; j < 4; ++j) {
      sW[w][0][q * 4 + j][nfk * 16 + lrow] = cL[nfk][j];
      sW[w][1][q * 4 + j][nfk * 16 + lrow] = cQ[nfk][j];
    }
  __syncthreads();

  // ---- epilogue 2: softmax + loss partials
  {
    const int b = tid >> 4, kk = tid & 15;
    float L0 = sW[0][0][b][kk]      + sW[1][0][b][kk]      + sW[2][0][b][kk]      + sW[3][0][b][kk];
    float L1 = sW[0][0][b][kk + 16] + sW[1][0][b][kk + 16] + sW[2][0][b][kk + 16] + sW[3][0][b][kk + 16];
    float Q0 = sW[0][1][b][kk]      + sW[1][1][b][kk]      + sW[2][1][b][kk]      + sW[3][1][b][kk];
    float Q1 = sW[0][1][b][kk + 16] + sW[1][1][b][kk + 16] + sW[2][1][b][kk + 16] + sW[3][1][b][kk + 16];
    float l0 = -(L0 + c3k[kk]);
    float l1 = -(L1 + c3k[kk + 16]);
    float mx = fmaxf(l0, l1);
    #pragma unroll
    for (int s = 8; s; s >>= 1) mx = fmaxf(mx, __shfl_xor(mx, s));
    float p0 = __expf(l0 - mx), p1 = __expf(l1 - mx);
    float ps = p0 + p1;
    #pragma unroll
    for (int s = 8; s; s >>= 1) ps += __shfl_xor(ps, s);
    float pi0 = p0 / ps + 1e-10f;
    float pi1 = p1 / ps + 1e-10f;
    float g = pi0 * (Q0 + ckk[kk]) + pi1 * (Q1 + ckk[kk + 16]);
    #pragma unroll
    for (int s = 8; s; s >>= 1) g += __shfl_xor(g, s);
    atomicAdd(&piP[kk], pi0);
    atomicAdd(&piP[kk + 16], pi1);
    if (kk == 0) atomicAdd(&gSum, g);
  }
  __syncthreads();
  if (tid < NK)  part[(size_t)tid * 512 + blockIdx.x] = piP[tid];
  if (tid == NK) part[(size_t)NK * 512 + blockIdx.x] = 0.5f * gSum;
}

// ---- kernel 2: final reduce (part[33][512], float4 rows, 4-way wave split) -
__global__ __launch_bounds__(256) void final_k(const float* __restrict__ part,
                                               float* __restrict__ out) {
  __shared__ double red[4][33];
  const int tid = threadIdx.x, lane = tid & 63, wv = tid >> 6;
  if (lane < 33) {
    const float4* p4 = reinterpret_cast<const float4*>(part + (size_t)lane * 512);
    double acc = 0.0;
    for (int i = wv * 32; i < wv * 32 + 32; ++i) {
      float4 v = p4[i];
      acc += (double)v.x + (double)v.y + (double)v.z + (double)v.w;
    }
    red[wv][lane] = acc;
  }
  __syncthreads();
  if (tid >= 64) return;
  double s = (tid < 33) ? (red[0][tid] + red[1][tid] + red[2][tid] + red[3][tid]) : 0.0;
  if (tid == 32) out[NB * ND] = (float)s;            // batch_gaussian_loss
  double t = 0.0;
  if (tid < 32) { double mk = s / (double)NB; t = mk * log(mk); }
  #pragma unroll
  for (int sh = 16; sh; sh >>= 1) t += __shfl_xor(t, sh);
  if (tid == 0) out[NB * ND + 1] = (float)(t / (double)NK);
}

extern "C" void kernel_launch(void* const* d_in, const int* in_sizes, int n_in,
                              void* d_out, int out_size, void* d_ws, size_t ws_size,
                              hipStream_t stream) {
  const float* x    = (const float*)d_in[0];
  const float* eps  = (const float*)d_in[1];
  const float* wmu  = (const float*)d_in[2];
  const float* bmu  = (const float*)d_in[3];
  const float* wsig = (const float*)d_in[4];
  const float* bsig = (const float*)d_in[5];
  const float* mu_c = (const float*)d_in[6];
  const float* lsc  = (const float*)d_in[7];
  float* out = (float*)d_out;

  char* ws = (char*)d_ws;
  __hip_bfloat16* wsw  = (__hip_bfloat16*)ws;                      // 256 KiB
  __hip_bfloat16* bcsw = (__hip_bfloat16*)(ws + (256u << 10));     // 32 KiB
  float* c3k  = (float*)(ws + (288u << 10));                       // 128 B
  float* ckk  = (float*)(ws + (288u << 10) + 256u);                // 128 B
  float* part = (float*)(ws + (288u << 10) + 512u);                // 66 KiB

  prep_k<<<544, 256, 0, stream>>>(wmu, wsig, wsw, mu_c, lsc, bcsw, c3k, ckk);
  mega_k<<<512, 256, 0, stream>>>(x, wsw, bmu, bsig, eps, bcsw, c3k, ckk, out, part);
  final_k<<<1, 256, 0, stream>>>(part, out);
}